// Round 6
// baseline (54.692 us; speedup 1.0000x reference)
//
#include <hip/hip_runtime.h>
#include <hip/hip_bf16.h>
#include <math.h>

typedef short short8 __attribute__((ext_vector_type(8)));
typedef float f32x4 __attribute__((ext_vector_type(4)));

#define NROW 4096
#define DIM  128
#define NCLS 64
#define CCAP 512
#define MAXM 128
#define NBT  64      // 64 row-blocks of 64 rows
#define NTILE 2080   // NBT*(NBT+1)/2 upper-tri 64x64 tiles

__device__ __forceinline__ unsigned short f2bf(float f) {
    unsigned u = __builtin_bit_cast(unsigned, f);
    unsigned r = (u + 0x7fffu + ((u >> 16) & 1u)) >> 16;   // RNE
    return (unsigned short)r;
}

__device__ __forceinline__ short8 pack8(const float4& a, const float4& b) {
    short8 h;
    h[0] = (short)f2bf(a.x); h[1] = (short)f2bf(a.y);
    h[2] = (short)f2bf(a.z); h[3] = (short)f2bf(a.w);
    h[4] = (short)f2bf(b.x); h[5] = (short)f2bf(b.y);
    h[6] = (short)f2bf(b.z); h[7] = (short)f2bf(b.w);
    return h;
}

// ---- row_neg: 64x64 upper-tri tiles; per-tile fp32->bf16 convert (no prep pass) ----
// diagonal blocks also scatter their rows into per-class lists
__global__ __launch_bounds__(256, 4) void rowneg_kernel(
        const float* __restrict__ X, const int* __restrict__ tgt,
        float* __restrict__ rn, int* __restrict__ ccnt, int* __restrict__ list)
{
    const int t = threadIdx.x;
    const int w = t >> 6, l = t & 63, lr = l & 15, lg = l >> 4;

    // invert triangular index: k -> (bi, bj), bi <= bj; off(bi) = bi*NBT - bi(bi-1)/2
    const int k = blockIdx.x;
    int bi = (int)(64.5f - sqrtf(64.5f * 64.5f - 2.0f * (float)k));
    if (bi < 0) bi = 0; if (bi > NBT - 1) bi = NBT - 1;
    while (bi < NBT - 1 && ((bi + 1) * NBT - (((bi + 1) * bi) >> 1)) <= k) ++bi;
    while (bi > 0 && (bi * NBT - ((bi * (bi - 1)) >> 1)) > k) --bi;
    const int bj = bi + (k - (bi * NBT - ((bi * (bi - 1)) >> 1)));
    const int gib = bi * 64, gjb = bj * 64;

    __shared__ __align__(16) unsigned short tA[64 * 128];
    __shared__ __align__(16) unsigned short tB[64 * 128];
    __shared__ float s_sqi[64], s_sqj[64];
    __shared__ float s_cacc[4][64];
    __shared__ int   s_ti[64], s_tj[64];

    // ---- stage: 128 logical rows (0-63 -> tA from gib, 64-127 -> tB from gjb) ----
    {
        const int row  = t >> 1;          // 0..127
        const int half = t & 1;           // 64-col half
        const int grow = (row < 64) ? (gib + row) : (gjb + row - 64);
        const float4* src = reinterpret_cast<const float4*>(X + (size_t)grow * DIM + half * 64);
        float4 buf[16];
        #pragma unroll
        for (int q = 0; q < 16; ++q) buf[q] = src[q];
        float p = 0.0f;
        #pragma unroll
        for (int q = 0; q < 16; ++q)
            p += buf[q].x * buf[q].x + buf[q].y * buf[q].y + buf[q].z * buf[q].z + buf[q].w * buf[q].w;
        p += __shfl_xor(p, 1);            // combine the two halves of the row
        unsigned short* dst = (row < 64) ? tA : tB;
        const int lrow = row & 63;
        #pragma unroll
        for (int q = 0; q < 8; ++q) {
            int c16 = half * 8 + q;
            *reinterpret_cast<short8*>(&dst[lrow * 128 + ((c16 ^ (lrow & 7)) * 8)]) =
                pack8(buf[2 * q], buf[2 * q + 1]);
        }
        if (half == 0) {
            if (row < 64) s_sqi[row] = p; else s_sqj[row - 64] = p;
        }
    }
    if (t < 64)       s_ti[t] = tgt[gib + t];
    else if (t < 128) s_tj[t - 64] = tgt[gjb + t - 64];
    else if (bi == bj && t < 192) {       // embedded class scatter (once per row)
        int row = gib + (t - 128);
        int cls = tgt[row];
        int p = atomicAdd(&ccnt[cls], 1);
        if (p < CCAP) list[cls * CCAP + p] = row;
    }
    __syncthreads();

    // ---- MFMA: wave w owns i-rows w*16..w*16+15 ----
    const int arow = w * 16 + lr;
    f32x4 C[4] = {};
    #pragma unroll
    for (int ks = 0; ks < 4; ++ks) {
        int c = ks * 4 + lg;
        short8 a = *reinterpret_cast<const short8*>(&tA[arow * 128 + ((c ^ (arow & 7)) * 8)]);
        #pragma unroll
        for (int fj = 0; fj < 4; ++fj) {
            int brow = fj * 16 + lr;
            short8 bb = *reinterpret_cast<const short8*>(&tB[brow * 128 + ((c ^ (brow & 7)) * 8)]);
            C[fj] = __builtin_amdgcn_mfma_f32_16x16x32_bf16(a, bb, C[fj], 0, 0, 0);
        }
    }

    // C[fj][r]: i = gib + w*16 + lg*4 + r, j = gjb + fj*16 + lr
    const int ibase = w * 16 + lg * 4;
    float sqi[4]; int ti[4];
    #pragma unroll
    for (int r = 0; r < 4; ++r) { sqi[r] = s_sqi[ibase + r]; ti[r] = s_ti[ibase + r]; }

    float racc[4] = {0.f, 0.f, 0.f, 0.f};
    float cacc[4] = {0.f, 0.f, 0.f, 0.f};
    #pragma unroll
    for (int fj = 0; fj < 4; ++fj) {
        int jl = fj * 16 + lr;
        float sqj = s_sqj[jl];
        int   tj  = s_tj[jl];
        int   gj  = gjb + jl;
        #pragma unroll
        for (int r = 0; r < 4; ++r) {
            int gi = gib + ibase + r;
            float d2 = fmaxf(sqi[r] + sqj - 2.0f * C[fj][r], 0.0f);
            float dist = __builtin_amdgcn_sqrtf(d2);
            float e = __expf(1.0f - dist);
            bool valid = (gi < gj) && (ti[r] != tj) && (d2 > 0.0f);
            e = valid ? e : 0.0f;
            racc[r] += e;
            cacc[fj] += e;
        }
    }

    // row sums: reduce across lr (16 lanes) -> global atomics
    #pragma unroll
    for (int r = 0; r < 4; ++r) {
        racc[r] += __shfl_xor(racc[r], 1);
        racc[r] += __shfl_xor(racc[r], 2);
        racc[r] += __shfl_xor(racc[r], 4);
        racc[r] += __shfl_xor(racc[r], 8);
    }
    if (lr == 0) {
        #pragma unroll
        for (int r = 0; r < 4; ++r) atomicAdd(&rn[gib + ibase + r], racc[r]);
    }
    // col sums: reduce across lg within wave, combine 4 waves via LDS
    #pragma unroll
    for (int fj = 0; fj < 4; ++fj) {
        cacc[fj] += __shfl_xor(cacc[fj], 16);
        cacc[fj] += __shfl_xor(cacc[fj], 32);
    }
    if (lg == 0) {
        #pragma unroll
        for (int fj = 0; fj < 4; ++fj) s_cacc[w][fj * 16 + lr] = cacc[fj];
    }
    __syncthreads();
    if (t < 64) {
        float cs = s_cacc[0][t] + s_cacc[1][t] + s_cacc[2][t] + s_cacc[3][t];
        if (cs != 0.0f) atomicAdd(&rn[gjb + t], cs);
    }
}

// ---- per-class positive loss; 2 blocks per class (h = p-row half); last block finalizes ----
__global__ __launch_bounds__(256) void loss_kernel(
        const float* __restrict__ X, const float* __restrict__ rn,
        const int* __restrict__ ccnt, const int* __restrict__ list,
        float* __restrict__ acc, unsigned* __restrict__ tick, float* __restrict__ out)
{
    const int c = blockIdx.x >> 1;
    const int h = blockIdx.x & 1;
    int m = ccnt[c]; if (m > CCAP) m = CCAP;
    const int mm = m < MAXM ? m : MAXM;
    const int nfj = (mm + 15) >> 4;

    __shared__ __align__(16) unsigned short tX[MAXM * DIM];
    __shared__ float sqg[MAXM], rng[MAXM];
    __shared__ int   s_idx[MAXM];
    __shared__ float s_red[16];

    const int t = threadIdx.x;
    const int w = t >> 6, l = t & 63, lr = l & 15, lg = l >> 4;

    float csum = 0.0f, cpairs = 0.0f;

    // h=1 has no p-rows when mm<=64 (and fallback is h=0's job): bare tick and leave
    if (h == 1 && mm <= 64) goto tickout;

    if (t < MAXM) s_idx[t] = (t < mm) ? list[c * CCAP + t] : 0;
    __syncthreads();

    // ---- gathered stage: 2 threads/row, fp32 load + convert + swizzled ds_write ----
    {
        const int row  = t >> 1;
        const int half = t & 1;
        if (row < mm) {
            const int ri = s_idx[row];
            const float4* src = reinterpret_cast<const float4*>(X + (size_t)ri * DIM + half * 64);
            float4 buf[16];
            #pragma unroll
            for (int q = 0; q < 16; ++q) buf[q] = src[q];
            float p = 0.0f;
            #pragma unroll
            for (int q = 0; q < 16; ++q)
                p += buf[q].x * buf[q].x + buf[q].y * buf[q].y + buf[q].z * buf[q].z + buf[q].w * buf[q].w;
            p += __shfl_xor(p, 1);
            #pragma unroll
            for (int q = 0; q < 8; ++q) {
                int c16 = half * 8 + q;
                *reinterpret_cast<short8*>(&tX[row * 128 + ((c16 ^ (row & 7)) * 8)]) =
                    pack8(buf[2 * q], buf[2 * q + 1]);
            }
            if (half == 0) { sqg[row] = p; rng[row] = rn[ri]; }
        } else if (half == 0 && row < MAXM) {
            sqg[row] = 0.0f; rng[row] = 0.0f;
        }
    }
    __syncthreads();

    {
        const int rowbase = h * 64 + w * 16;
        if (rowbase < mm) {                              // wave-uniform guard
            f32x4 C[8] = {};
            const int arow = rowbase + lr;
            #pragma unroll
            for (int ks = 0; ks < 4; ++ks) {
                int cb = ks * 4 + lg;
                short8 a = *reinterpret_cast<const short8*>(&tX[arow * DIM + ((cb ^ (arow & 7)) * 8)]);
                #pragma unroll
                for (int fj = 0; fj < 8; ++fj) {
                    if (fj < nfj) {
                        int brow = fj * 16 + lr;
                        short8 bb = *reinterpret_cast<const short8*>(&tX[brow * DIM + ((cb ^ (brow & 7)) * 8)]);
                        C[fj] = __builtin_amdgcn_mfma_f32_16x16x32_bf16(a, bb, C[fj], 0, 0, 0);
                    }
                }
            }
            #pragma unroll
            for (int fj = 0; fj < 8; ++fj) {
                if (fj < nfj) {
                    int q = fj * 16 + lr;
                    #pragma unroll
                    for (int r = 0; r < 4; ++r) {
                        int p = rowbase + lg * 4 + r;
                        if (q < mm && p < q) {
                            float d2 = fmaxf(sqg[p] + sqg[q] - 2.0f * C[fj][r], 0.0f);
                            float dist = __builtin_amdgcn_sqrtf(d2);
                            float J = __logf(rng[p] + rng[q]) + dist;
                            if (J > 0.0f) csum += J * J;
                            cpairs += 1.0f;
                        }
                    }
                }
            }
        }

        // fallback for improbably large classes (fp32, h=0 only, never hot)
        if (h == 0 && m > MAXM) {
            for (int q = MAXM; q < m; ++q) {
                int rq = list[c * CCAP + q];
                const float4* xb = reinterpret_cast<const float4*>(X + (size_t)rq * DIM);
                float sqq = 0.0f;
                for (int kq = 0; kq < 32; ++kq) {
                    float4 bv = xb[kq];
                    sqq += bv.x * bv.x + bv.y * bv.y + bv.z * bv.z + bv.w * bv.w;
                }
                float rnq = rn[rq];
                for (int p = t; p < q; p += 256) {
                    int rp = list[c * CCAP + p];
                    const float4* xa = reinterpret_cast<const float4*>(X + (size_t)rp * DIM);
                    float d = 0.0f, sqp = 0.0f;
                    for (int kq = 0; kq < 32; ++kq) {
                        float4 av = xa[kq], bv = xb[kq];
                        d += av.x * bv.x + av.y * bv.y + av.z * bv.z + av.w * bv.w;
                        sqp += av.x * av.x + av.y * av.y + av.z * av.z + av.w * av.w;
                    }
                    float d2 = fmaxf(sqp + sqq - 2.0f * d, 0.0f);
                    float dist = __builtin_amdgcn_sqrtf(d2);
                    float J = __logf(rn[rp] + rnq) + dist;
                    if (J > 0.0f) csum += J * J;
                    cpairs += 1.0f;
                }
            }
        }

        #pragma unroll
        for (int mr = 1; mr < 64; mr <<= 1) {
            csum   += __shfl_xor(csum, mr);
            cpairs += __shfl_xor(cpairs, mr);
        }
        if (l == 0) { s_red[w] = csum; s_red[8 + w] = cpairs; }
        __syncthreads();
        if (t == 0 && (s_red[0] + s_red[1] + s_red[2] + s_red[3] != 0.0f ||
                       s_red[8] + s_red[9] + s_red[10] + s_red[11] != 0.0f)) {
            atomicAdd(&acc[0], s_red[0] + s_red[1] + s_red[2] + s_red[3]);
            atomicAdd(&acc[1], s_red[8] + s_red[9] + s_red[10] + s_red[11]);
        }
    }

tickout:
    __threadfence();
    if (t == 0) {
        unsigned old = atomicAdd(tick, 1u);
        if (old == 2 * NCLS - 1) {
            float s  = atomicAdd(&acc[0], 0.0f);   // coherent device-scope reads
            float n2 = atomicAdd(&acc[1], 0.0f);
            out[0] = s / (2.0f * n2);              // len_p = 2 * upper-tri count
        }
    }
}

extern "C" void kernel_launch(void* const* d_in, const int* in_sizes, int n_in,
                              void* d_out, int out_size, void* d_ws, size_t ws_size,
                              hipStream_t stream)
{
    const float* X  = (const float*)d_in[0];
    const int* tgt  = (const int*)d_in[1];
    float* out      = (float*)d_out;

    char* ws = (char*)d_ws;
    float*    rn   = (float*)ws;                       // 16 KB  (zeroed)
    float*    acc  = rn + NROW;                        // 8 B    (zeroed)
    unsigned* tick = (unsigned*)(acc + 2);             // 4 B    (zeroed)
    int*      ccnt = (int*)(tick + 2);                 // 256 B  (zeroed)
    int*      list = ccnt + NCLS;                      // 128 KB (gated by ccnt)

    hipMemsetAsync(ws, 0, (size_t)((char*)list - ws), stream);
    rowneg_kernel<<<NTILE, 256, 0, stream>>>(X, tgt, rn, ccnt, list);
    loss_kernel<<<2 * NCLS, 256, 0, stream>>>(X, rn, ccnt, list, acc, tick, out);
}

// Round 7
// 48.957 us; speedup vs baseline: 1.1171x; 1.1171x over previous
//
#include <hip/hip_runtime.h>
#include <hip/hip_bf16.h>
#include <math.h>

typedef short short8 __attribute__((ext_vector_type(8)));
typedef float f32x4 __attribute__((ext_vector_type(4)));

#define NROW 4096
#define DIM  128
#define NCLS 64
#define MAXM 128
#define LCAP 256
#define NBT  64      // 64 row-blocks of 64 rows
#define NTILE 2080   // NBT*(NBT+1)/2 upper-tri 64x64 tiles
#define PS   66      // per-row partial-slot stride (65 slots used)

__device__ __forceinline__ unsigned short f2bf(float f) {
    unsigned u = __builtin_bit_cast(unsigned, f);
    unsigned r = (u + 0x7fffu + ((u >> 16) & 1u)) >> 16;   // RNE
    return (unsigned short)r;
}

__device__ __forceinline__ short8 pack8(const float4& a, const float4& b) {
    short8 h;
    h[0] = (short)f2bf(a.x); h[1] = (short)f2bf(a.y);
    h[2] = (short)f2bf(a.z); h[3] = (short)f2bf(a.w);
    h[4] = (short)f2bf(b.x); h[5] = (short)f2bf(b.y);
    h[6] = (short)f2bf(b.z); h[7] = (short)f2bf(b.w);
    return h;
}

// ---- row_neg partials: 64x64 upper-tri tiles; write-only P slots, no atomics ----
// P[row*PS + s]: s in [0, R]  = j-side partial from tile (s, R(row))
//                s in (R, 64] = i-side partial from tile (R(row), s-1)
__global__ __launch_bounds__(256, 4) void rowneg_kernel(
        const float* __restrict__ X, const int* __restrict__ tgt,
        float* __restrict__ P, float* __restrict__ acc, unsigned* __restrict__ tick)
{
    const int t = threadIdx.x;
    const int w = t >> 6, l = t & 63, lr = l & 15, lg = l >> 4;

    // invert triangular index: k -> (bi, bj), bi <= bj
    const int k = blockIdx.x;
    int bi = (int)(64.5f - sqrtf(64.5f * 64.5f - 2.0f * (float)k));
    if (bi < 0) bi = 0; if (bi > NBT - 1) bi = NBT - 1;
    while (bi < NBT - 1 && ((bi + 1) * NBT - (((bi + 1) * bi) >> 1)) <= k) ++bi;
    while (bi > 0 && (bi * NBT - ((bi * (bi - 1)) >> 1)) > k) --bi;
    const int bj = bi + (k - (bi * NBT - ((bi * (bi - 1)) >> 1)));
    const int gib = bi * 64, gjb = bj * 64;

    __shared__ __align__(16) unsigned short tA[64 * 128];
    __shared__ __align__(16) unsigned short tB[64 * 128];
    __shared__ float s_sqi[64], s_sqj[64];
    __shared__ float s_cacc[4][64];
    __shared__ int   s_ti[64], s_tj[64];

    // ---- stage: 128 logical rows (0-63 -> tA from gib, 64-127 -> tB from gjb) ----
    {
        const int row  = t >> 1;          // 0..127
        const int half = t & 1;           // 64-col half
        const int grow = (row < 64) ? (gib + row) : (gjb + row - 64);
        const float4* src = reinterpret_cast<const float4*>(X + (size_t)grow * DIM + half * 64);
        float4 buf[16];
        #pragma unroll
        for (int q = 0; q < 16; ++q) buf[q] = src[q];
        float p = 0.0f;
        #pragma unroll
        for (int q = 0; q < 16; ++q)
            p += buf[q].x * buf[q].x + buf[q].y * buf[q].y + buf[q].z * buf[q].z + buf[q].w * buf[q].w;
        p += __shfl_xor(p, 1);            // combine the two halves of the row
        unsigned short* dst = (row < 64) ? tA : tB;
        const int lrow = row & 63;
        #pragma unroll
        for (int q = 0; q < 8; ++q) {
            int c16 = half * 8 + q;
            *reinterpret_cast<short8*>(&dst[lrow * 128 + ((c16 ^ (lrow & 7)) * 8)]) =
                pack8(buf[2 * q], buf[2 * q + 1]);
        }
        if (half == 0) {
            if (row < 64) s_sqi[row] = p; else s_sqj[row - 64] = p;
        }
    }
    if (t < 64)       s_ti[t] = tgt[gib + t];
    else if (t < 128) s_tj[t - 64] = tgt[gjb + t - 64];
    else if (k == 0 && t < 131) {          // zero accumulators once (only loss writes them)
        if (t == 128) acc[0] = 0.0f;
        if (t == 129) acc[1] = 0.0f;
        if (t == 130) tick[0] = 0u;
    }
    __syncthreads();

    // ---- MFMA: wave w owns i-rows w*16..w*16+15 ----
    const int arow = w * 16 + lr;
    f32x4 C[4] = {};
    #pragma unroll
    for (int ks = 0; ks < 4; ++ks) {
        int c = ks * 4 + lg;
        short8 a = *reinterpret_cast<const short8*>(&tA[arow * 128 + ((c ^ (arow & 7)) * 8)]);
        #pragma unroll
        for (int fj = 0; fj < 4; ++fj) {
            int brow = fj * 16 + lr;
            short8 bb = *reinterpret_cast<const short8*>(&tB[brow * 128 + ((c ^ (brow & 7)) * 8)]);
            C[fj] = __builtin_amdgcn_mfma_f32_16x16x32_bf16(a, bb, C[fj], 0, 0, 0);
        }
    }

    // C[fj][r]: i = gib + w*16 + lg*4 + r, j = gjb + fj*16 + lr
    const int ibase = w * 16 + lg * 4;
    float sqi[4]; int ti[4];
    #pragma unroll
    for (int r = 0; r < 4; ++r) { sqi[r] = s_sqi[ibase + r]; ti[r] = s_ti[ibase + r]; }

    float racc[4] = {0.f, 0.f, 0.f, 0.f};
    float cacc[4] = {0.f, 0.f, 0.f, 0.f};
    #pragma unroll
    for (int fj = 0; fj < 4; ++fj) {
        int jl = fj * 16 + lr;
        float sqj = s_sqj[jl];
        int   tj  = s_tj[jl];
        int   gj  = gjb + jl;
        #pragma unroll
        for (int r = 0; r < 4; ++r) {
            int gi = gib + ibase + r;
            float d2 = fmaxf(sqi[r] + sqj - 2.0f * C[fj][r], 0.0f);
            float dist = __builtin_amdgcn_sqrtf(d2);
            float e = __expf(1.0f - dist);
            bool valid = (gi < gj) && (ti[r] != tj) && (d2 > 0.0f);
            e = valid ? e : 0.0f;
            racc[r] += e;
            cacc[fj] += e;
        }
    }

    // i-side row partials: reduce across lr (16 lanes) -> store to slot bj+1
    #pragma unroll
    for (int r = 0; r < 4; ++r) {
        racc[r] += __shfl_xor(racc[r], 1);
        racc[r] += __shfl_xor(racc[r], 2);
        racc[r] += __shfl_xor(racc[r], 4);
        racc[r] += __shfl_xor(racc[r], 8);
    }
    if (lr == 0) {
        #pragma unroll
        for (int r = 0; r < 4; ++r)
            P[(size_t)(gib + ibase + r) * PS + (bj + 1)] = racc[r];
    }
    // j-side col partials: reduce across lg within wave, combine 4 waves, store slot bi
    #pragma unroll
    for (int fj = 0; fj < 4; ++fj) {
        cacc[fj] += __shfl_xor(cacc[fj], 16);
        cacc[fj] += __shfl_xor(cacc[fj], 32);
    }
    if (lg == 0) {
        #pragma unroll
        for (int fj = 0; fj < 4; ++fj) s_cacc[w][fj * 16 + lr] = cacc[fj];
    }
    __syncthreads();
    if (t < 64) {
        float cs = s_cacc[0][t] + s_cacc[1][t] + s_cacc[2][t] + s_cacc[3][t];
        P[(size_t)(gjb + t) * PS + bi] = cs;
    }
}

// ---- per-class positive loss; 2 blocks/class (h = p-row half); last block finalizes ----
__global__ __launch_bounds__(256) void loss_kernel(
        const float* __restrict__ X, const int* __restrict__ tgt,
        const float* __restrict__ P,
        float* __restrict__ acc, unsigned* __restrict__ tick, float* __restrict__ out)
{
    const int c = blockIdx.x >> 1;
    const int h = blockIdx.x & 1;

    __shared__ __align__(16) unsigned short tX[MAXM * DIM];
    __shared__ float sqg[MAXM], rng[MAXM];
    __shared__ int   s_idx[LCAP];
    __shared__ int   s_wsum[4];
    __shared__ float s_red[16];

    const int t = threadIdx.x;
    const int w = t >> 6, l = t & 63, lr = l & 15, lg = l >> 4;

    float csum = 0.0f, cpairs = 0.0f;
    int mtot, mm, nfj;

    // ---- build ordered class row list by scanning tgt (no global scatter state) ----
    {
        const int rbase = t * 16;
        int tv[16];
        {
            int4 a = *reinterpret_cast<const int4*>(tgt + rbase);
            int4 b = *reinterpret_cast<const int4*>(tgt + rbase + 4);
            int4 d = *reinterpret_cast<const int4*>(tgt + rbase + 8);
            int4 e = *reinterpret_cast<const int4*>(tgt + rbase + 12);
            tv[0]=a.x; tv[1]=a.y; tv[2]=a.z; tv[3]=a.w;
            tv[4]=b.x; tv[5]=b.y; tv[6]=b.z; tv[7]=b.w;
            tv[8]=d.x; tv[9]=d.y; tv[10]=d.z; tv[11]=d.w;
            tv[12]=e.x; tv[13]=e.y; tv[14]=e.z; tv[15]=e.w;
        }
        int cnt = 0;
        #pragma unroll
        for (int k2 = 0; k2 < 16; ++k2) cnt += (tv[k2] == c) ? 1 : 0;
        int sc = cnt;                                   // wave inclusive scan
        #pragma unroll
        for (int d2 = 1; d2 < 64; d2 <<= 1) {
            int u = __shfl_up(sc, d2);
            if (l >= d2) sc += u;
        }
        if (l == 63) s_wsum[w] = sc;
        __syncthreads();
        int woff = 0;
        if (w > 0) woff += s_wsum[0];
        if (w > 1) woff += s_wsum[1];
        if (w > 2) woff += s_wsum[2];
        int off = woff + sc - cnt;                      // exclusive prefix
        #pragma unroll
        for (int k2 = 0; k2 < 16; ++k2) {
            if (tv[k2] == c) { if (off < LCAP) s_idx[off] = rbase + k2; ++off; }
        }
        mtot = s_wsum[0] + s_wsum[1] + s_wsum[2] + s_wsum[3];
    }
    mm  = mtot < MAXM ? mtot : MAXM;
    nfj = (mm + 15) >> 4;
    __syncthreads();                                    // s_idx ready

    // h=1 has no p-rows when mm<=64 (fallback is h=0's job): bare tick and leave
    if (h == 1 && mm <= 64) goto tickout;

    // ---- rn for gathered rows: sum the 65 tile partials ----
    if (t < MAXM) {
        float s2 = 0.0f;
        if (t < mm) {
            const float* pp = P + (size_t)s_idx[t] * PS;
            #pragma unroll 5
            for (int s = 0; s < 65; ++s) s2 += pp[s];
        }
        rng[t] = s2;
    }

    // ---- gathered stage: 2 threads/row, fp32 load + convert + swizzled ds_write ----
    {
        const int row  = t >> 1;
        const int half = t & 1;
        if (row < mm) {
            const int ri = s_idx[row];
            const float4* src = reinterpret_cast<const float4*>(X + (size_t)ri * DIM + half * 64);
            float4 buf[16];
            #pragma unroll
            for (int q = 0; q < 16; ++q) buf[q] = src[q];
            float p = 0.0f;
            #pragma unroll
            for (int q = 0; q < 16; ++q)
                p += buf[q].x * buf[q].x + buf[q].y * buf[q].y + buf[q].z * buf[q].z + buf[q].w * buf[q].w;
            p += __shfl_xor(p, 1);
            #pragma unroll
            for (int q = 0; q < 8; ++q) {
                int c16 = half * 8 + q;
                *reinterpret_cast<short8*>(&tX[row * 128 + ((c16 ^ (row & 7)) * 8)]) =
                    pack8(buf[2 * q], buf[2 * q + 1]);
            }
            if (half == 0) sqg[row] = p;
        } else if (half == 0 && row < MAXM) {
            sqg[row] = 0.0f;
        }
    }
    __syncthreads();

    {
        const int rowbase = h * 64 + w * 16;
        if (rowbase < mm) {                              // wave-uniform guard
            f32x4 C[8] = {};
            const int arow = rowbase + lr;
            #pragma unroll
            for (int ks = 0; ks < 4; ++ks) {
                int cb = ks * 4 + lg;
                short8 a = *reinterpret_cast<const short8*>(&tX[arow * DIM + ((cb ^ (arow & 7)) * 8)]);
                #pragma unroll
                for (int fj = 0; fj < 8; ++fj) {
                    if (fj < nfj) {
                        int brow = fj * 16 + lr;
                        short8 bb = *reinterpret_cast<const short8*>(&tX[brow * DIM + ((cb ^ (brow & 7)) * 8)]);
                        C[fj] = __builtin_amdgcn_mfma_f32_16x16x32_bf16(a, bb, C[fj], 0, 0, 0);
                    }
                }
            }
            #pragma unroll
            for (int fj = 0; fj < 8; ++fj) {
                if (fj < nfj) {
                    int q = fj * 16 + lr;
                    #pragma unroll
                    for (int r = 0; r < 4; ++r) {
                        int p = rowbase + lg * 4 + r;
                        if (q < mm && p < q) {
                            float d2 = fmaxf(sqg[p] + sqg[q] - 2.0f * C[fj][r], 0.0f);
                            float dist = __builtin_amdgcn_sqrtf(d2);
                            float J = __logf(rng[p] + rng[q]) + dist;
                            if (J > 0.0f) csum += J * J;
                            cpairs += 1.0f;
                        }
                    }
                }
            }
        }

        // fallback for improbably large classes (fp32, h=0 only, practically unreachable)
        if (h == 0 && mtot > MAXM) {
            int mq = mtot < LCAP ? mtot : LCAP;
            for (int q = MAXM; q < mq; ++q) {
                int rq = s_idx[q];
                const float4* xb = reinterpret_cast<const float4*>(X + (size_t)rq * DIM);
                float sqq = 0.0f;
                for (int kq = 0; kq < 32; ++kq) {
                    float4 bv = xb[kq];
                    sqq += bv.x * bv.x + bv.y * bv.y + bv.z * bv.z + bv.w * bv.w;
                }
                float rnq = 0.0f;
                for (int s = 0; s < 65; ++s) rnq += P[(size_t)rq * PS + s];
                for (int p2 = t; p2 < q; p2 += 256) {
                    int rp = s_idx[p2];
                    const float4* xa = reinterpret_cast<const float4*>(X + (size_t)rp * DIM);
                    float d = 0.0f, sqp = 0.0f;
                    for (int kq = 0; kq < 32; ++kq) {
                        float4 av = xa[kq], bv = xb[kq];
                        d += av.x * bv.x + av.y * bv.y + av.z * bv.z + av.w * bv.w;
                        sqp += av.x * av.x + av.y * av.y + av.z * av.z + av.w * av.w;
                    }
                    float rnp = 0.0f;
                    for (int s = 0; s < 65; ++s) rnp += P[(size_t)rp * PS + s];
                    float d2 = fmaxf(sqp + sqq - 2.0f * d, 0.0f);
                    float dist = __builtin_amdgcn_sqrtf(d2);
                    float J = __logf(rnp + rnq) + dist;
                    if (J > 0.0f) csum += J * J;
                    cpairs += 1.0f;
                }
            }
        }

        #pragma unroll
        for (int mr = 1; mr < 64; mr <<= 1) {
            csum   += __shfl_xor(csum, mr);
            cpairs += __shfl_xor(cpairs, mr);
        }
        if (l == 0) { s_red[w] = csum; s_red[8 + w] = cpairs; }
        __syncthreads();
        if (t == 0) {
            float bs = s_red[0] + s_red[1] + s_red[2] + s_red[3];
            float bc = s_red[8] + s_red[9] + s_red[10] + s_red[11];
            if (bs != 0.0f || bc != 0.0f) {
                atomicAdd(&acc[0], bs);
                atomicAdd(&acc[1], bc);
            }
        }
    }

tickout:
    __threadfence();
    if (t == 0) {
        unsigned old = atomicAdd(tick, 1u);
        if (old == 2 * NCLS - 1) {
            float s  = atomicAdd(&acc[0], 0.0f);   // coherent device-scope reads
            float n2 = atomicAdd(&acc[1], 0.0f);
            out[0] = s / (2.0f * n2);              // len_p = 2 * upper-tri count
        }
    }
}

extern "C" void kernel_launch(void* const* d_in, const int* in_sizes, int n_in,
                              void* d_out, int out_size, void* d_ws, size_t ws_size,
                              hipStream_t stream)
{
    const float* X  = (const float*)d_in[0];
    const int* tgt  = (const int*)d_in[1];
    float* out      = (float*)d_out;

    float*    P    = (float*)d_ws;                     // 4096*66*4 B ≈ 1.06 MB (fully overwritten)
    float*    acc  = P + (size_t)NROW * PS;            // 2 floats (zeroed by rowneg block 0)
    unsigned* tick = (unsigned*)(acc + 2);             // 1 uint   (zeroed by rowneg block 0)

    rowneg_kernel<<<NTILE, 256, 0, stream>>>(X, tgt, P, acc, tick);
    loss_kernel<<<2 * NCLS, 256, 0, stream>>>(X, tgt, P, acc, tick, out);
}